// Round 1
// 1031.800 us; speedup vs baseline: 1.0802x; 1.0802x over previous
//
#include <hip/hip_runtime.h>

typedef _Float16 f16;
typedef _Float16 f16x8 __attribute__((ext_vector_type(8)));
typedef float f32x4 __attribute__((ext_vector_type(4)));

#define DEVI static __device__ __forceinline__

// async global->LDS 16B: lane i lands at (wave-uniform lds base) + i*16
DEVI void async_ld16(const void* g, void* l) {
  __builtin_amdgcn_global_load_lds(
      (const __attribute__((address_space(1))) unsigned int*)g,
      (__attribute__((address_space(3))) unsigned int*)l, 16, 0, 0);
}

// Byte offset of (row, logical k-quad) in a 128x32-f16 tile (64 B rows),
// XOR-swizzled so 16-lane frag reads are only 2-way bank aliased (free).
DEVI int sw_off(int row, int q) {
  return row * 64 + ((q ^ ((row >> 1) & 3)) << 4);
}

// ======================= 128x128 kernel (offset + linear GEMMs) =============
// C[M,N] (fp32 split-K partials) = A[M,K] * B[N,K]^T, B fp16 async-staged.
// A fp16 (async) or fp32 (in-kernel cvt — only for the small offset GEMM).
// 128x128 block tile, 4 waves of 64x64, 16x16x32 f16 MFMA, BK=32.
template<bool A_F32>
__global__ __launch_bounds__(256, 4)
void gemm_bt(const void* __restrict__ Aptr, const f16* __restrict__ Bt,
             float* __restrict__ Cpart, int ldK, int Nvalid,
             int mTiles, int nTiles, int kPerSplit, int Mtot) {
  __shared__ __align__(16) f16 As[128 * 32];
  __shared__ __align__(16) f16 Bs[128 * 32];

  int nb = gridDim.x;
  int bid = (blockIdx.x & 7) * (nb >> 3) + (blockIdx.x >> 3);
  int ms = bid % mTiles; bid /= mTiles;
  int ns = bid % nTiles; bid /= nTiles;
  int ks = bid;
  int m0 = ms * 128, n0 = ns * 128;
  int k0 = ks * kPerSplit;

  int tid = threadIdx.x;
  int w = tid >> 6, lane = tid & 63;
  int wrow = (w >> 1) * 64, wcol = (w & 1) * 64;
  int lrow = lane & 15, lquad = lane >> 4;

  f32x4 acc[4][4];
#pragma unroll
  for (int i = 0; i < 4; ++i)
#pragma unroll
    for (int j = 0; j < 4; ++j) acc[i][j] = (f32x4){0.f, 0.f, 0.f, 0.f};

  for (int kk = k0; kk < k0 + kPerSplit; kk += 32) {
    __syncthreads();  // previous iter's LDS reads done
#pragma unroll
    for (int s = 0; s < 2; ++s) {
      int rl = w * 32 + s * 16 + (lane >> 2);
      int qp = lane & 3;
      int q = qp ^ ((rl >> 1) & 3);
      int rb = n0 + rl; if (rb > Nvalid - 1) rb = Nvalid - 1;  // clamp
      async_ld16(Bt + (size_t)rb * ldK + kk + q * 8, &Bs[(w * 32 + s * 16) * 32]);
    }
    if (!A_F32) {
      const f16* Ah = (const f16*)Aptr;
#pragma unroll
      for (int s = 0; s < 2; ++s) {
        int rl = w * 32 + s * 16 + (lane >> 2);
        int qp = lane & 3;
        int q = qp ^ ((rl >> 1) & 3);
        async_ld16(Ah + (size_t)(m0 + rl) * ldK + kk + q * 8, &As[(w * 32 + s * 16) * 32]);
      }
    } else {
      const float* Af = (const float*)Aptr;
      int r = tid >> 1, half = tid & 1;
      const float* src = Af + (size_t)(m0 + r) * ldK + kk + half * 16;
#pragma unroll
      for (int u2 = 0; u2 < 2; ++u2) {
        f32x4 a = *(const f32x4*)(src + u2 * 8);
        f32x4 b = *(const f32x4*)(src + u2 * 8 + 4);
        f16x8 h;
        h[0] = (f16)a[0]; h[1] = (f16)a[1]; h[2] = (f16)a[2]; h[3] = (f16)a[3];
        h[4] = (f16)b[0]; h[5] = (f16)b[1]; h[6] = (f16)b[2]; h[7] = (f16)b[3];
        *(f16x8*)((char*)As + sw_off(r, half * 2 + u2)) = h;
      }
    }
    __syncthreads();  // drains vmcnt (async LDS) + lgkmcnt (ds_write)

    f16x8 af[4], bf[4];
#pragma unroll
    for (int i = 0; i < 4; ++i)
      af[i] = *(const f16x8*)((const char*)As + sw_off(wrow + i * 16 + lrow, lquad));
#pragma unroll
    for (int j = 0; j < 4; ++j)
      bf[j] = *(const f16x8*)((const char*)Bs + sw_off(wcol + j * 16 + lrow, lquad));
#pragma unroll
    for (int i = 0; i < 4; ++i)
#pragma unroll
      for (int j = 0; j < 4; ++j)
        acc[i][j] = __builtin_amdgcn_mfma_f32_16x16x32_f16(af[i], bf[j], acc[i][j], 0, 0, 0);
  }

  size_t base = (size_t)ks * Mtot * Nvalid;
#pragma unroll
  for (int i = 0; i < 4; ++i) {
    int row = m0 + wrow + i * 16 + lquad * 4;
#pragma unroll
    for (int j = 0; j < 4; ++j) {
      int col = n0 + wcol + j * 16 + lrow;
      if (col < Nvalid) {
#pragma unroll
        for (int r = 0; r < 4; ++r)
          Cpart[base + (size_t)(row + r) * Nvalid + col] = acc[i][j][r];
      }
    }
  }
}

// ======================= 256x256 8-phase kernel (deform GEMM) ===============
// C[M,N] fp32 split-K partials = A[M,K]*B[N,K]^T, both fp16.
// 256x256 tile, BK=64, 512 threads = 8 waves (2Mx4N), per-wave 128x64 out.
// LDS 128 KiB: per operand 2 dbuf x 2 kk-planes x [256 rows x 32 f16] (64B rows,
// quad-XOR swizzled as in gemm_bt). Stage unit = one 16KB kk-plane = 2
// global_load_lds instr/wave. Schedule (per K-tile t, buf b=t&1, 4 phases):
//   ph0: dsr A(b,k0) rh0 + B(b,k0) all-ct ; stage B(b^1,k1)@t+1 ; MFMA rh0*kk0
//   ph1: dsr A(b,k0) rh1                  ; stage A(b^1,k1)@t+1 ; MFMA rh1*kk0 ; vmcnt(8)
//   ph2: dsr A(b,k1) rh0 + B(b,k1)        ; stage B(b,k0)@t+2   ; MFMA rh0*kk1
//   ph3: dsr A(b,k1) rh1                  ; stage A(b,k0)@t+2   ; MFMA rh1*kk1 ; vmcnt(8)
// vmcnt(8) = 4 stage-calls in flight; every consumed plane was staged 5-6
// phases earlier and is guaranteed landed at the preceding vmcnt+barrier.
// Epilogue drains 8 -> 4 -> 0. Requires NT=kPerSplit/64 even, >=4.
#define DSR(dst, addr, off) \
  asm volatile("ds_read_b128 %0, %1 offset:" off : "=&v"(dst) : "v"(addr))

#define PHASE(BUF, KK, RH, RDB, STG, VMF, VMS, BAR) do {                      \
    unsigned aP = aAddr + (unsigned)((BUF)*32768 + (KK)*16384 + (RH)*4096);   \
    DSR(af[0], aP, "0");    DSR(af[1], aP, "1024");                           \
    DSR(af[2], aP, "2048"); DSR(af[3], aP, "3072");                           \
    if (RDB) {                                                                \
      unsigned bP = bAddr + (unsigned)((BUF)*32768 + (KK)*16384);             \
      DSR(bf[0], bP, "0");    DSR(bf[1], bP, "1024");                         \
      DSR(bf[2], bP, "2048"); DSR(bf[3], bP, "3072");                         \
    }                                                                         \
    STG;                                                                      \
    if (BAR) __builtin_amdgcn_s_barrier();                                    \
    asm volatile("s_waitcnt lgkmcnt(0)");                                     \
    __builtin_amdgcn_sched_barrier(0);                                        \
    __builtin_amdgcn_s_setprio(1);                                            \
    _Pragma("unroll")                                                         \
    for (int i_ = 0; i_ < 4; ++i_) {                                          \
      _Pragma("unroll")                                                       \
      for (int j_ = 0; j_ < 4; ++j_)                                          \
        acc[(RH)*4 + i_][j_] = __builtin_amdgcn_mfma_f32_16x16x32_f16(        \
            af[i_], bf[j_], acc[(RH)*4 + i_][j_], 0, 0, 0);                   \
    }                                                                         \
    __builtin_amdgcn_s_setprio(0);                                            \
    if (VMF) asm volatile("s_waitcnt vmcnt(" VMS ")");                        \
    if (BAR) __builtin_amdgcn_s_barrier();                                    \
  } while (0)

__global__ __launch_bounds__(512, 2)
void gemm256(const f16* __restrict__ A, const f16* __restrict__ Bt,
             float* __restrict__ Cpart, int ldK,
             int mTiles, int nTiles, int kPerSplit, int Mtot, int Ntot) {
  __shared__ __align__(16) f16 lds[65536];  // 128 KiB: A [0,64K), B [64K,128K)

  int nb = gridDim.x;
  int bid = (blockIdx.x & 7) * (nb >> 3) + (blockIdx.x >> 3);  // XCD swizzle
  int ms = bid % mTiles; bid /= mTiles;
  int ns = bid % nTiles; bid /= nTiles;
  int ks = bid;
  int m0 = ms * 256, n0 = ns * 256;
  long k0 = (long)ks * kPerSplit;
  int NT = kPerSplit >> 6;

  int tid = threadIdx.x;
  int w = tid >> 6, lane = tid & 63;
  int wrow = (w >> 2) * 128, wcol = (w & 3) * 64;
  int lrow = lane & 15;
  unsigned sq = (unsigned)((((lane >> 4) ^ ((lrow >> 1) & 3))) << 4);

  // LDS byte addresses for ds_read (low 32 bits of flat shared ptr = LDS offset)
  char* ldsc = (char*)&lds[0];
  unsigned ldsBase = (unsigned)(uintptr_t)(void*)&lds[0];
  unsigned aAddr = ldsBase + (unsigned)((wrow + lrow) * 64) + sq;
  unsigned bAddr = ldsBase + 65536u + (unsigned)((wcol + lrow) * 64) + sq;

  // per-lane pre-swizzled global srcs for staging (k0 folded in); rows rs,rs+16
  const f16* Ab = A + (size_t)m0 * ldK + k0;
  const f16* Bb = Bt + (size_t)n0 * ldK + k0;
  int rs = (w * 2) * 16 + (lane >> 2);
  int qg = ((lane & 3) ^ ((rs >> 1) & 3)) * 8;   // (rs>>1)&3 invariant to +16
  const f16* a0 = Ab + (size_t)rs * ldK + qg;
  const f16* b0 = Bb + (size_t)rs * ldK + qg;
  const f16* a1 = a0 + (size_t)16 * ldK;
  const f16* b1 = b0 + (size_t)16 * ldK;

#define STGP(p0, p1, LOFF, KOFF) do {                                \
    async_ld16(p0 + (KOFF), ldsc + (LOFF) + (w * 2) * 1024);         \
    async_ld16(p1 + (KOFF), ldsc + (LOFF) + (w * 2) * 1024 + 1024);  \
  } while (0)
#define STG_A(BUF, KK, KT) STGP(a0, a1, (BUF)*32768 + (KK)*16384, (KT)*64 + (KK)*32)
#define STG_B(BUF, KK, KT) STGP(b0, b1, 65536 + (BUF)*32768 + (KK)*16384, (KT)*64 + (KK)*32)

  f32x4 acc[8][4];
#pragma unroll
  for (int i = 0; i < 8; ++i)
#pragma unroll
    for (int j = 0; j < 4; ++j) acc[i][j] = (f32x4){0.f, 0.f, 0.f, 0.f};

  f16x8 af[4], bf[4];

  // prologue: K-tile 0 fully + K-tile 1 kk0 (6 planes, 12 loads/wave);
  // vmcnt(8) drains B(0,0),A(0,0) -> needed by t0.ph0/ph1
  STG_B(0, 0, 0); STG_A(0, 0, 0);
  STG_B(0, 1, 0); STG_A(0, 1, 0);
  STG_B(1, 0, 1); STG_A(1, 0, 1);
  asm volatile("s_waitcnt vmcnt(8)");
  __builtin_amdgcn_s_barrier();

  // main loop: 2 K-tiles / iteration; stages reach t+3
  for (int t = 0; t + 3 < NT; t += 2) {
    PHASE(0, 0, 0, 1, STG_B(1, 1, t + 1), 0, "0", 1);
    PHASE(0, 0, 1, 0, STG_A(1, 1, t + 1), 1, "8", 1);
    PHASE(0, 1, 0, 1, STG_B(0, 0, t + 2), 0, "0", 1);
    PHASE(0, 1, 1, 0, STG_A(0, 0, t + 2), 1, "8", 1);
    PHASE(1, 0, 0, 1, STG_B(0, 1, t + 2), 0, "0", 1);
    PHASE(1, 0, 1, 0, STG_A(0, 1, t + 2), 1, "8", 1);
    PHASE(1, 1, 0, 1, STG_B(1, 0, t + 3), 0, "0", 1);
    PHASE(1, 1, 1, 0, STG_A(1, 0, t + 3), 1, "8", 1);
  }

  // epilogue: tile NT-2 (buf0) still stages NT-1's kk1; drain 8 -> 4 -> 0
  {
    int km1 = NT - 1;
    PHASE(0, 0, 0, 1, STG_B(1, 1, km1), 0, "0", 1);
    PHASE(0, 0, 1, 0, STG_A(1, 1, km1), 1, "8", 1);
    PHASE(0, 1, 0, 1, (void)0,          0, "0", 1);
    PHASE(0, 1, 1, 0, (void)0,          1, "4", 1);
    PHASE(1, 0, 0, 1, (void)0,          0, "0", 1);
    PHASE(1, 0, 1, 0, (void)0,          1, "0", 1);
    PHASE(1, 1, 0, 1, (void)0,          0, "0", 1);
    PHASE(1, 1, 1, 0, (void)0,          0, "0", 0);
  }

  // C/D layout: col = lane&15, row = (lane>>4)*4 + reg (m89/m91-verified)
  size_t cbase = (size_t)ks * ((size_t)Mtot * Ntot);
#pragma unroll
  for (int rt = 0; rt < 8; ++rt) {
    int row = m0 + wrow + rt * 16 + (lane >> 4) * 4;
#pragma unroll
    for (int ct = 0; ct < 4; ++ct) {
      int col = n0 + wcol + ct * 16 + lrow;
#pragma unroll
      for (int r = 0; r < 4; ++r)
        Cpart[cbase + (size_t)(row + r) * Ntot + col] = acc[rt][ct][r];
    }
  }
#undef STG_B
#undef STG_A
#undef STGP
}
#undef PHASE
#undef DSR

// ======================= helpers ============================================
__global__ void cvt_f32_to_f16(const float* __restrict__ in, f16* __restrict__ out, long n) {
  long idx = ((long)blockIdx.x * blockDim.x + threadIdx.x) * 8;
  if (idx + 8 <= n) {
    f32x4 a = *(const f32x4*)(in + idx);
    f32x4 b = *(const f32x4*)(in + idx + 4);
    f16x8 o;
    o[0] = (f16)a[0]; o[1] = (f16)a[1]; o[2] = (f16)a[2]; o[3] = (f16)a[3];
    o[4] = (f16)b[0]; o[5] = (f16)b[1]; o[6] = (f16)b[2]; o[7] = (f16)b[3];
    *(f16x8*)(out + idx) = o;
  }
}

// Build deform-conv columns, LDS-staged.
__global__ __launch_bounds__(256, 4)
void build_cols(const float* __restrict__ x, const float* __restrict__ offs,
                f16* __restrict__ cols) {
  int b = blockIdx.x >> 3;
  int c0 = (blockIdx.x & 7) * 128;
  __shared__ __align__(16) float s_x[128 * 49];
  __shared__ __align__(16) int   s_idx[49][4];
  __shared__ __align__(16) float s_w[49][4];
  int t = threadIdx.x;
  if (t < 49) {
    float dy = offs[b * 98 + 2 * t];
    float dx = offs[b * 98 + 2 * t + 1];
    float py = dy + (float)(t / 7);
    float px = dx + (float)(t % 7);
    float fy0 = floorf(py), fx0 = floorf(px);
    int y0 = (int)fy0, x0 = (int)fx0;
    float fy = py - fy0, fx = px - fx0;
#pragma unroll
    for (int di = 0; di < 2; ++di)
#pragma unroll
      for (int dj = 0; dj < 2; ++dj) {
        int yi = y0 + di, xi = x0 + dj;
        bool valid = (yi >= 0) && (yi < 7) && (xi >= 0) && (xi < 7);
        int yc = yi < 0 ? 0 : (yi > 6 ? 6 : yi);
        int xc = xi < 0 ? 0 : (xi > 6 ? 6 : xi);
        float wy = di ? fy : 1.f - fy;
        float wx = dj ? fx : 1.f - fx;
        s_idx[t][di * 2 + dj] = yc * 7 + xc;
        s_w[t][di * 2 + dj] = valid ? wy * wx : 0.f;
      }
  }
  const f32x4* xs = (const f32x4*)(x + (size_t)b * 50176 + c0 * 49);
  f32x4* s4 = (f32x4*)s_x;
#pragma unroll
  for (int i = 0; i < 6; ++i) s4[t + i * 256] = xs[t + i * 256];
  if (t < 32) s4[1536 + t] = xs[1536 + t];
  __syncthreads();

  f16* cb = cols + (size_t)b * 50176 + c0 * 49;
#pragma unroll
  for (int i = 0; i < 25; ++i) {
    int o = t + i * 256;
    if (o < 6272) {
      unsigned c = (unsigned)o / 49u;
      unsigned p = (unsigned)o - c * 49u;
      int4  gi = *(const int4*)s_idx[p];
      float4 gw = *(const float4*)s_w[p];
      const float* row = s_x + c * 49;
      float v = gw.x * row[gi.x] + gw.y * row[gi.y]
              + gw.z * row[gi.z] + gw.w * row[gi.w];
      cb[o] = (f16)v;
    }
  }
}

// sum split-K partials (+bias) (+softshrink), write fp32 and/or fp16
__global__ void combine_k(const float* __restrict__ parts, int nparts, size_t pstride,
                          const float* __restrict__ bias, float* __restrict__ outf,
                          f16* __restrict__ outh, int total, int cols, int shrink) {
  int i = blockIdx.x * 256 + threadIdx.x;
  if (i >= total) return;
  float s = 0.f;
  for (int p = 0; p < nparts; ++p) s += parts[(size_t)p * pstride + i];
  if (bias) s += bias[i % cols];
  if (shrink) s = s > 0.5f ? s - 0.5f : (s < -0.5f ? s + 0.5f : 0.f);
  if (outf) outf[i] = s;
  if (outh) outh[i] = (f16)s;
}

extern "C" void kernel_launch(void* const* d_in, const int* in_sizes, int n_in,
                              void* d_out, int out_size, void* d_ws, size_t ws_size,
                              hipStream_t stream) {
  const float* x  = (const float*)d_in[0];
  const float* ow = (const float*)d_in[1];
  const float* dw = (const float*)d_in[2];
  const float* db = (const float*)d_in[3];
  const float* lw = (const float*)d_in[4];
  const float* lb = (const float*)d_in[5];
  float* out = (float*)d_out;

  const long KX = 50176;  // CIN*49
  char* ws = (char*)d_ws;
  size_t off = 0;
  auto alloc = [&](size_t bytes) {
    char* p = ws + off;
    off = (off + bytes + 255) & ~(size_t)255;
    return p;
  };
  f16*   dw_h = (f16*)  alloc((size_t)2048 * KX * 2);       // 205.5 MB
  f16*   ow_h = (f16*)  alloc((size_t)98 * KX * 2);         //   9.8 MB
  f16*   lw_h = (f16*)  alloc((size_t)2048 * 2048 * 2);     //   8.4 MB
  f16*   cols = (f16*)  alloc((size_t)1024 * KX * 2);       // 102.8 MB
  float* y1p  = (float*)alloc((size_t)8 * 1024 * 2048 * 4); //  67.1 MB
  f16*   y1h  = (f16*)  alloc((size_t)1024 * 2048 * 2);     //   4.2 MB
  float* offs = (float*)y1p;                                //   0.4 MB (alias)
  float* offp = (float*)((char*)y1p + (1u << 20));          //  39.4 MB (alias)
  float* y2p  = (float*)cols;                               //  67.1 MB (alias)
  if (off > ws_size) return;

  // 1) fp32 -> fp16 conversions
  long n_dw = 2048L * KX, n_ow = 98L * KX, n_lw = 2048L * 2048L;
  cvt_f32_to_f16<<<(unsigned)(n_dw / 8 / 256), 256, 0, stream>>>(dw, dw_h, n_dw);
  cvt_f32_to_f16<<<(unsigned)(n_ow / 8 / 256), 256, 0, stream>>>(ow, ow_h, n_ow);
  cvt_f32_to_f16<<<(unsigned)(n_lw / 8 / 256), 256, 0, stream>>>(lw, lw_h, n_lw);

  // 2) offset GEMM: [1024 x 98] = x(fp32) * ow^T, split-K 98
  gemm_bt<true><<<8 * 1 * 98, 256, 0, stream>>>(
      x, ow_h, offp, 50176, 98, 8, 1, 512, 1024);
  combine_k<<<(1024 * 98 + 255) / 256, 256, 0, stream>>>(
      offp, 98, (size_t)1024 * 98, nullptr, offs, nullptr, 1024 * 98, 98, 0);

  // 3) bilinear column build
  build_cols<<<1024 * 8, 256, 0, stream>>>(x, offs, cols);

  // 4) deform GEMM: [1024 x 2048] = cols * dw_h^T, 256^2 8-phase, split-K 8
  //    grid = 4 mTiles x 8 nTiles x 8 ksplits = 256 blocks (1/CU)
  gemm256<<<256, 512, 0, stream>>>(
      cols, dw_h, y1p, 50176, 4, 8, 6272, 1024, 2048);
  combine_k<<<(2097152 + 255) / 256, 256, 0, stream>>>(
      y1p, 8, (size_t)2097152, db, nullptr, y1h, 2097152, 2048, 0);

  // 5) linear GEMM: [1024 x 2048] = y1(fp16) * lw^T, split-K 8, bias+softshrink
  gemm_bt<false><<<8 * 16 * 8, 256, 0, stream>>>(
      y1h, lw_h, y2p, 2048, 2048, 8, 16, 256, 1024);
  combine_k<<<(2097152 + 255) / 256, 256, 0, stream>>>(
      y2p, 8, (size_t)2097152, lb, out, nullptr, 2097152, 2048, 1);
}